// Round 2
// baseline (1866.772 us; speedup 1.0000x reference)
//
#include <hip/hip_runtime.h>
#include <hip/hip_bf16.h>

#define T_TOK 1024
#define H_DIM 2048
#define E_NUM 32
#define F_DIM 1408
#define G_NUM 8
#define TOPKG 3
#define TOPK  6
#define FS_DIM 2816
#define SCALE_F 16.0f

#define BM 256
#define BK 32

typedef __attribute__((ext_vector_type(8))) __bf16 bf16x8;
typedef __attribute__((ext_vector_type(4))) float f32x4;

__device__ __forceinline__ unsigned short f2bf(float f) {
    union { float f; unsigned u; } v; v.f = f;
    unsigned r = v.u + 0x7fffu + ((v.u >> 16) & 1u);
    return (unsigned short)(r >> 16);
}

// pack two floats -> two bf16 (RNE, bit-identical to f2bf pair) in ~5 VALU
__device__ __forceinline__ unsigned pk2(float a, float b) {
    union { float f; unsigned u; } x, y; x.f = a; y.f = b;
    unsigned ra = x.u + 0x7fffu + ((x.u >> 16) & 1u);
    unsigned rb = y.u + 0x7fffu + ((y.u >> 16) & 1u);
    return __builtin_amdgcn_perm(rb, ra, 0x07060302);  // [rb.hi16 : ra.hi16]
}

__device__ __forceinline__ bf16x8 ld_frag(const unsigned short* p) {
    union { uint4 u; bf16x8 v; } x;
    x.u = *(const uint4*)p;
    return x.v;
}

__device__ __forceinline__ f32x4 mfma16(bf16x8 a, bf16x8 b, f32x4 c) {
    return __builtin_amdgcn_mfma_f32_16x16x32_bf16(a, b, c, 0, 0, 0);
}

__device__ __forceinline__ void gload_lds16(const void* g, void* l) {
    __builtin_amdgcn_global_load_lds(
        (const __attribute__((address_space(1))) unsigned int*)g,
        (__attribute__((address_space(3))) unsigned int*)l, 16, 0, 0);
}

// ---------------- prep: zero counters + convert x to bf16 ----------------
__global__ void prep_kernel(const float* __restrict__ x, unsigned short* __restrict__ xb,
                            int* __restrict__ cnt, int* __restrict__ cnt2) {
    if (blockIdx.x == 0) {
        if (threadIdx.x < E_NUM) cnt[threadIdx.x] = 0;
        else if (threadIdx.x < 2 * E_NUM) cnt2[threadIdx.x - E_NUM] = 0;
    }
    int i = blockIdx.x * blockDim.x + threadIdx.x;  // over T*H/4
    float4 v = ((const float4*)x)[i];
    uint2 o;
    o.x = (unsigned)f2bf(v.x) | ((unsigned)f2bf(v.y) << 16);
    o.y = (unsigned)f2bf(v.z) | ((unsigned)f2bf(v.w) << 16);
    ((uint2*)xb)[i] = o;
}

// ---------------- router: logits + softmax + grouped topk ----------------
__global__ void router_kernel(const float* __restrict__ x, const float* __restrict__ wg,
                              float* __restrict__ topk_w, int* __restrict__ topk_ids,
                              int* __restrict__ cnt) {
    int t = blockIdx.x;
    __shared__ float xs[H_DIM];
    __shared__ float logits[E_NUM];
    const float* xr = x + (size_t)t * H_DIM;
    for (int i = threadIdx.x; i < H_DIM / 4; i += 256)
        ((float4*)xs)[i] = ((const float4*)xr)[i];
    __syncthreads();
    int wave = threadIdx.x >> 6, lane = threadIdx.x & 63;
    for (int eo = 0; eo < 8; ++eo) {
        int e = wave * 8 + eo;
        const float* w = wg + (size_t)e * H_DIM;
        float s = 0.f;
        for (int i = lane; i < H_DIM; i += 64) s += xs[i] * w[i];
        for (int d = 32; d; d >>= 1) s += __shfl_down(s, d);
        if (lane == 0) logits[e] = s;
    }
    __syncthreads();
    if (threadIdx.x == 0) {
        float sc[E_NUM];
        float mx = -1e30f;
        for (int e = 0; e < E_NUM; ++e) mx = fmaxf(mx, logits[e]);
        float sum = 0.f;
        for (int e = 0; e < E_NUM; ++e) { sc[e] = expf(logits[e] - mx); sum += sc[e]; }
        float inv = 1.0f / sum;
        for (int e = 0; e < E_NUM; ++e) sc[e] *= inv;
        float gs[G_NUM];
        for (int g = 0; g < G_NUM; ++g) {
            float m = sc[g * 4];
            for (int j = 1; j < 4; ++j) m = fmaxf(m, sc[g * 4 + j]);
            gs[g] = m;
        }
        unsigned gmask = 0;
        for (int r = 0; r < TOPKG; ++r) {
            int best = 0; float bv = -1e30f;
            for (int g = 0; g < G_NUM; ++g)
                if (!((gmask >> g) & 1) && gs[g] > bv) { bv = gs[g]; best = g; }
            gmask |= 1u << best;
        }
        for (int e = 0; e < E_NUM; ++e)
            if (!((gmask >> (e >> 2)) & 1)) sc[e] = -1.0f;
        for (int r = 0; r < TOPK; ++r) {
            int best = 0; float bv = -1e30f;
            for (int e = 0; e < E_NUM; ++e)
                if (sc[e] > bv) { bv = sc[e]; best = e; }
            topk_w[t * TOPK + r] = bv;
            topk_ids[t * TOPK + r] = best;
            sc[best] = -2.0f;
            atomicAdd(&cnt[best], 1);
        }
    }
}

// ---------------- scan ----------------
__global__ void scan_kernel(const int* __restrict__ cnt, int* __restrict__ off) {
    if (threadIdx.x == 0) {
        int a = 0;
        for (int e = 0; e < E_NUM; ++e) { off[e] = a; a += cnt[e]; }
        off[E_NUM] = a;
    }
}

// ---------------- scatter ----------------
__global__ void scatter_kernel(const int* __restrict__ topk_ids, const float* __restrict__ topk_w,
                               const int* __restrict__ off, int* __restrict__ cnt2,
                               int* __restrict__ perm_token, float* __restrict__ perm_w,
                               int* __restrict__ dest) {
    int i = blockIdx.x * blockDim.x + threadIdx.x;
    if (i >= T_TOK * TOPK) return;
    int t = i / TOPK;
    int e = topk_ids[i];
    float w = topk_w[i];
    int pos = off[e] + atomicAdd(&cnt2[e], 1);
    perm_token[pos] = t;
    perm_w[pos] = w * SCALE_F;
    dest[pos] = i;
}

// ---------------- gate_up GEMM with fused SiLU*mul ----------------
// Block tile: 256 rows x (64 left + 64 right cols), K-step 32, 512 threads.
// Waves: wm = wv>>1 (4 m-quarters of 64 rows), wn = wv&1 (2 n-halves of 32 cols).
// A staged via global_load_lds into linear [256][32] bf16; B fp32->bf16 transpose-staged.
template<bool ROUTED, int N2, int FD>
__global__ __launch_bounds__(512, 4)
void gate_up_kernel(const unsigned short* __restrict__ xb, const float* __restrict__ Bw,
                    unsigned short* __restrict__ act, const int* __restrict__ perm_token,
                    const int* __restrict__ off) {
    int e = ROUTED ? blockIdx.z : 0;
    int nb = blockIdx.x * 64;
    if (nb >= FD) return;                 // grid.x padded to multiple of 8 (XCD align)
    int s0 = 0, M = T_TOK;
    if (ROUTED) { s0 = off[e]; M = off[e + 1] - s0; }
    int mbase = blockIdx.y * BM;
    if (mbase >= M) return;
    const float* Bp = Bw + (size_t)e * H_DIM * N2;

    __shared__ unsigned short As[256 * 32];   // linear, 64B rows -> conflict-free b128 reads
    __shared__ unsigned short Bs[128 * 32];

    int tid = threadIdx.x;
    int lane = tid & 63;
    int wv = tid >> 6;
    int wm = wv >> 1, wn = wv & 1;
    int quad = lane >> 4;
    int l16 = lane & 15;

    f32x4 acc[4][4];
#pragma unroll
    for (int i = 0; i < 4; ++i)
#pragma unroll
        for (int j = 0; j < 4; ++j) acc[i][j] = (f32x4){0.f, 0.f, 0.f, 0.f};

    // A: thread t covers row (i*128 + t>>2), 8-elem segment (t&3). Clamp OOB rows
    // to a valid token (garbage only pollutes never-stored output rows).
    const unsigned short* aSrc0;
    const unsigned short* aSrc1;
    {
        int g0 = mbase + (tid >> 2);
        int g1 = g0 + 128;
        int t0, t1;
        if (ROUTED) {
            t0 = perm_token[s0 + ((g0 < M) ? g0 : 0)];
            t1 = perm_token[s0 + ((g1 < M) ? g1 : 0)];
        } else {
            t0 = (g0 < M) ? g0 : 0;
            t1 = (g1 < M) ? g1 : 0;
        }
        aSrc0 = xb + (size_t)t0 * H_DIM + (tid & 3) * 8;
        aSrc1 = xb + (size_t)t1 * H_DIM + (tid & 3) * 8;
    }
    char* aDst0 = (char*)As + tid * 16;
    char* aDst1 = (char*)As + 8192 + tid * 16;

    // B: thread covers col bn, k-rows bk0..bk0+7
    int bn = tid & 127;
    int bk0 = (tid >> 7) * 8;
    int bcol = (bn < 64) ? (nb + bn) : (FD + nb + (bn - 64));
    const float* bSrc = Bp + (size_t)bk0 * N2 + bcol;
    uint4* bDst = (uint4*)(&Bs[bn * 32 + bk0]);

    for (int k0 = 0; k0 < H_DIM; k0 += BK) {
        gload_lds16(aSrc0 + k0, aDst0);
        gload_lds16(aSrc1 + k0, aDst1);
        {
            float f0 = bSrc[0 * (size_t)N2], f1 = bSrc[1 * (size_t)N2];
            float f2 = bSrc[2 * (size_t)N2], f3 = bSrc[3 * (size_t)N2];
            float f4 = bSrc[4 * (size_t)N2], f5 = bSrc[5 * (size_t)N2];
            float f6 = bSrc[6 * (size_t)N2], f7 = bSrc[7 * (size_t)N2];
            uint4 w;
            w.x = pk2(f0, f1); w.y = pk2(f2, f3);
            w.z = pk2(f4, f5); w.w = pk2(f6, f7);
            *bDst = w;
        }
        bSrc += (size_t)BK * N2;
        __syncthreads();
        bf16x8 af[4];
#pragma unroll
        for (int i = 0; i < 4; ++i)
            af[i] = ld_frag(&As[(wm * 64 + i * 16 + l16) * 32 + quad * 8]);
#pragma unroll
        for (int j = 0; j < 4; ++j) {
            int n = (j < 2) ? (wn * 32 + j * 16 + l16) : (64 + wn * 32 + (j - 2) * 16 + l16);
            bf16x8 bfr = ld_frag(&Bs[n * 32 + quad * 8]);
#pragma unroll
            for (int i = 0; i < 4; ++i)
                acc[i][j] = mfma16(af[i], bfr, acc[i][j]);
        }
        __syncthreads();
    }

    // epilogue: act[row][col] = silu(left) * right  (bf16)
#pragma unroll
    for (int i = 0; i < 4; ++i) {
#pragma unroll
        for (int r = 0; r < 4; ++r) {
            int row = wm * 64 + i * 16 + quad * 4 + r;
            int g = mbase + row;
            if (g < M) {
                unsigned short* ap = act + (size_t)(s0 + g) * FD + nb + wn * 32 + l16;
#pragma unroll
                for (int j = 0; j < 2; ++j) {
                    float L = acc[i][j][r];
                    float R = acc[i][j + 2][r];
                    float s = L / (1.0f + __expf(-L));
                    ap[j * 16] = f2bf(s * R);
                }
            }
        }
    }
}

// ---------------- down GEMM ----------------
// Block tile: 256 rows x 128 cols, K-step 32, 512 threads.
template<bool ROUTED, int K>
__global__ __launch_bounds__(512, 4)
void down_kernel(const unsigned short* __restrict__ act, const float* __restrict__ Bw,
                 float* __restrict__ outp, const float* __restrict__ perm_w,
                 const int* __restrict__ dest, const int* __restrict__ off) {
    int e = ROUTED ? blockIdx.z : 0;
    int s0 = 0, M = T_TOK;
    if (ROUTED) { s0 = off[e]; M = off[e + 1] - s0; }
    int mbase = blockIdx.y * BM;
    if (mbase >= M) return;
    int nb = blockIdx.x * 128;
    const float* Bp = Bw + (size_t)e * K * H_DIM;

    __shared__ unsigned short As[256 * 32];
    __shared__ unsigned short Bs[128 * 32];

    int tid = threadIdx.x;
    int lane = tid & 63;
    int wv = tid >> 6;
    int wm = wv >> 1, wn = wv & 1;
    int quad = lane >> 4;
    int l16 = lane & 15;

    f32x4 acc[4][4];
#pragma unroll
    for (int i = 0; i < 4; ++i)
#pragma unroll
        for (int j = 0; j < 4; ++j) acc[i][j] = (f32x4){0.f, 0.f, 0.f, 0.f};

    const unsigned short* aSrc0;
    const unsigned short* aSrc1;
    {
        int g0 = mbase + (tid >> 2);
        int g1 = g0 + 128;
        int r0 = s0 + ((g0 < M) ? g0 : 0);
        int r1 = s0 + ((g1 < M) ? g1 : 0);
        aSrc0 = act + (size_t)r0 * K + (tid & 3) * 8;
        aSrc1 = act + (size_t)r1 * K + (tid & 3) * 8;
    }
    char* aDst0 = (char*)As + tid * 16;
    char* aDst1 = (char*)As + 8192 + tid * 16;

    int bn = tid & 127;
    int bk0 = (tid >> 7) * 8;
    const float* bSrc = Bp + (size_t)bk0 * H_DIM + nb + bn;
    uint4* bDst = (uint4*)(&Bs[bn * 32 + bk0]);

    for (int k0 = 0; k0 < K; k0 += BK) {
        gload_lds16(aSrc0 + k0, aDst0);
        gload_lds16(aSrc1 + k0, aDst1);
        {
            float f0 = bSrc[0 * (size_t)H_DIM], f1 = bSrc[1 * (size_t)H_DIM];
            float f2 = bSrc[2 * (size_t)H_DIM], f3 = bSrc[3 * (size_t)H_DIM];
            float f4 = bSrc[4 * (size_t)H_DIM], f5 = bSrc[5 * (size_t)H_DIM];
            float f6 = bSrc[6 * (size_t)H_DIM], f7 = bSrc[7 * (size_t)H_DIM];
            uint4 w;
            w.x = pk2(f0, f1); w.y = pk2(f2, f3);
            w.z = pk2(f4, f5); w.w = pk2(f6, f7);
            *bDst = w;
        }
        bSrc += (size_t)BK * H_DIM;
        __syncthreads();
        bf16x8 af[4];
#pragma unroll
        for (int i = 0; i < 4; ++i)
            af[i] = ld_frag(&As[(wm * 64 + i * 16 + l16) * 32 + quad * 8]);
#pragma unroll
        for (int j = 0; j < 4; ++j) {
            int n = wn * 64 + j * 16 + l16;
            bf16x8 bfr = ld_frag(&Bs[n * 32 + quad * 8]);
#pragma unroll
            for (int i = 0; i < 4; ++i)
                acc[i][j] = mfma16(af[i], bfr, acc[i][j]);
        }
        __syncthreads();
    }

#pragma unroll
    for (int i = 0; i < 4; ++i) {
#pragma unroll
        for (int r = 0; r < 4; ++r) {
            int row = wm * 64 + i * 16 + quad * 4 + r;
            int g = mbase + row;
            if (g < M) {
                float w = ROUTED ? perm_w[s0 + g] : 1.0f;
                int drow = ROUTED ? dest[s0 + g] : g;
                float* op = outp + (size_t)drow * H_DIM + nb + wn * 64 + l16;
#pragma unroll
                for (int j = 0; j < 4; ++j)
                    op[j * 16] = acc[i][j][r] * w;
            }
        }
    }
}

// ---------------- combine: out += sum_k partial[t*6+k] ----------------
__global__ void combine_kernel(float* __restrict__ outp, const float* __restrict__ partial) {
    int t = blockIdx.x;
    const float4* p0 = (const float4*)(partial + (size_t)t * TOPK * H_DIM);
    float4* o = (float4*)(outp + (size_t)t * H_DIM);
    for (int i = threadIdx.x; i < H_DIM / 4; i += 256) {
        float4 v = o[i];
#pragma unroll
        for (int k = 0; k < TOPK; ++k) {
            float4 p = p0[(size_t)k * (H_DIM / 4) + i];
            v.x += p.x; v.y += p.y; v.z += p.z; v.w += p.w;
        }
        o[i] = v;
    }
}

extern "C" void kernel_launch(void* const* d_in, const int* in_sizes, int n_in,
                              void* d_out, int out_size, void* d_ws, size_t ws_size,
                              hipStream_t stream) {
    const float* x   = (const float*)d_in[0];
    const float* wg  = (const float*)d_in[1];
    const float* w1  = (const float*)d_in[2];
    const float* w2  = (const float*)d_in[3];
    const float* ws1 = (const float*)d_in[4];
    const float* ws2 = (const float*)d_in[5];
    float* out = (float*)d_out;

    char* p = (char*)d_ws;
    auto alloc = [&](size_t bytes) {
        char* r = p;
        p += (bytes + 255) & ~(size_t)255;
        return r;
    };
    unsigned short* xb      = (unsigned short*)alloc((size_t)T_TOK * H_DIM * 2);
    float*          topk_w  = (float*)alloc((size_t)T_TOK * TOPK * 4);
    int*            topkid  = (int*)alloc((size_t)T_TOK * TOPK * 4);
    int*            cnt     = (int*)alloc(E_NUM * 4);
    int*            cnt2    = (int*)alloc(E_NUM * 4);
    int*            offs    = (int*)alloc((E_NUM + 1) * 4);
    int*            permtok = (int*)alloc((size_t)T_TOK * TOPK * 4);
    float*          permw   = (float*)alloc((size_t)T_TOK * TOPK * 4);
    int*            dest    = (int*)alloc((size_t)T_TOK * TOPK * 4);
    unsigned short* act_r   = (unsigned short*)alloc((size_t)T_TOK * TOPK * F_DIM * 2);
    unsigned short* act_s   = (unsigned short*)alloc((size_t)T_TOK * FS_DIM * 2);
    float*          partial = (float*)alloc((size_t)T_TOK * TOPK * H_DIM * 4);

    prep_kernel<<<(T_TOK * H_DIM / 4) / 256, 256, 0, stream>>>(x, xb, cnt, cnt2);
    router_kernel<<<T_TOK, 256, 0, stream>>>(x, wg, topk_w, topkid, cnt);
    scan_kernel<<<1, 64, 0, stream>>>(cnt, offs);
    scatter_kernel<<<(T_TOK * TOPK + 255) / 256, 256, 0, stream>>>(topkid, topk_w, offs, cnt2,
                                                                   permtok, permw, dest);
    // routed gate_up: grid.x padded 22->24 so same-B blocks share an XCD (L2 reuse)
    gate_up_kernel<true, 2 * F_DIM, F_DIM><<<dim3(24, 4, E_NUM), 512, 0, stream>>>(
        xb, w1, act_r, permtok, offs);
    // shared gate_up: grid.x padded 44->48
    gate_up_kernel<false, 2 * FS_DIM, FS_DIM><<<dim3(48, 4, 1), 512, 0, stream>>>(
        xb, ws1, act_s, nullptr, nullptr);
    // shared down -> d_out
    down_kernel<false, FS_DIM><<<dim3(16, 4, 1), 512, 0, stream>>>(
        act_s, ws2, out, nullptr, nullptr, nullptr);
    // routed down -> partial (scaled by topk_w * 16)
    down_kernel<true, F_DIM><<<dim3(16, 4, E_NUM), 512, 0, stream>>>(
        act_r, w2, partial, permw, dest, offs);
    // combine
    combine_kernel<<<T_TOK, 256, 0, stream>>>(out, partial);
}